// Round 1
// baseline (439.761 us; speedup 1.0000x reference)
//
#include <hip/hip_runtime.h>

// Inverse 2D Haar DWT (pywt idwt2 'haar' closed form).
// Inputs (dict order): x=cA (a), LH=cH (h), HL=cV (v), HH=cD (d),
// each (16,64,128,128) fp32. Output (16,64,256,256) fp32.
//   out[2i,2j]     = (a + v + h + d) * 0.5
//   out[2i,2j+1]   = (a - v + h - d) * 0.5
//   out[2i+1,2j]   = (a + v - h - d) * 0.5
//   out[2i+1,2j+1] = (a - v - h + d) * 0.5
//
// One thread handles 4 consecutive input cols (float4 load x4 inputs)
// and writes 2 output rows x 8 cols (float4 store x4). Coalesced both ways.

#define IN_W   128
#define OUT_W  256
#define VPR    (IN_W / 4)   // 32 float4-groups per input row

__global__ __launch_bounds__(256) void idwt2_haar_kernel(
    const float* __restrict__ pa,   // cA  (x)
    const float* __restrict__ ph,   // cH  (LH)
    const float* __restrict__ pv,   // cV  (HL)
    const float* __restrict__ pd,   // cD  (HH)
    float* __restrict__ out,
    int n_vec)                      // total float4 groups = N_in / 4
{
    int t = blockIdx.x * blockDim.x + threadIdx.x;
    int stride = gridDim.x * blockDim.x;
    for (; t < n_vec; t += stride) {
        int row = t >> 5;          // t / VPR   : global input row
        int q   = t & 31;          // t % VPR   : float4 index within row
        int in_off = row * IN_W + q * 4;

        float4 va = *(const float4*)(pa + in_off);
        float4 vh = *(const float4*)(ph + in_off);
        float4 vv = *(const float4*)(pv + in_off);
        float4 vd = *(const float4*)(pd + in_off);

        int p  = row >> 7;         // (B*C) plane index
        int hr = row & 127;        // input row within plane
        int out_even = p * (OUT_W * OUT_W) + (2 * hr) * OUT_W + q * 8;

        float A[4]  = {va.x, va.y, va.z, va.w};
        float Hc[4] = {vh.x, vh.y, vh.z, vh.w};
        float Vc[4] = {vv.x, vv.y, vv.z, vv.w};
        float D[4]  = {vd.x, vd.y, vd.z, vd.w};

        float top[8], bot[8];
#pragma unroll
        for (int k = 0; k < 4; ++k) {
            float a = A[k], h = Hc[k], v = Vc[k], d = D[k];
            top[2 * k]     = (a + v + h + d) * 0.5f;  // ee
            top[2 * k + 1] = (a - v + h - d) * 0.5f;  // eo
            bot[2 * k]     = (a + v - h - d) * 0.5f;  // oe
            bot[2 * k + 1] = (a - v - h + d) * 0.5f;  // oo
        }

        *(float4*)(out + out_even)              = make_float4(top[0], top[1], top[2], top[3]);
        *(float4*)(out + out_even + 4)          = make_float4(top[4], top[5], top[6], top[7]);
        *(float4*)(out + out_even + OUT_W)      = make_float4(bot[0], bot[1], bot[2], bot[3]);
        *(float4*)(out + out_even + OUT_W + 4)  = make_float4(bot[4], bot[5], bot[6], bot[7]);
    }
}

extern "C" void kernel_launch(void* const* d_in, const int* in_sizes, int n_in,
                              void* d_out, int out_size, void* d_ws, size_t ws_size,
                              hipStream_t stream) {
    const float* pa = (const float*)d_in[0];  // x   = cA
    const float* ph = (const float*)d_in[1];  // LH  = cH
    const float* pv = (const float*)d_in[2];  // HL  = cV
    const float* pd = (const float*)d_in[3];  // HH  = cD
    float* out = (float*)d_out;

    int n_in_elems = in_sizes[0];             // 16*64*128*128
    int n_vec = n_in_elems / 4;               // 4,194,304

    const int block = 256;
    int blocks_needed = (n_vec + block - 1) / block;   // 16384
    int grid = blocks_needed < 16384 ? blocks_needed : 16384;

    idwt2_haar_kernel<<<grid, block, 0, stream>>>(pa, ph, pv, pd, out, n_vec);
}

// Round 2
// 428.181 us; speedup vs baseline: 1.0270x; 1.0270x over previous
//
#include <hip/hip_runtime.h>

// Inverse 2D Haar DWT (pywt idwt2 'haar' closed form).
// Inputs (dict order): x=cA (a), LH=cH (h), HL=cV (v), HH=cD (d),
// each (16,64,128,128) fp32. Output (16,64,256,256) fp32.
//   out[2i,2j]     = (a + v + h + d) * 0.5
//   out[2i,2j+1]   = (a - v + h - d) * 0.5
//   out[2i+1,2j]   = (a + v - h - d) * 0.5
//   out[2i+1,2j+1] = (a - v - h + d) * 0.5
//
// Mapping (round 1 fix — dense stores): one thread handles 2 input cols
// (float2 loads from each of 4 inputs = 8 B/lane, 512 B dense per wave-load)
// and writes ONE float4 per output row (16 B/lane). A wave's 64 lanes cover
// 1024 contiguous bytes per store instruction — full cachelines, no RFO.

#define IN_W   128
#define OUT_W  256
#define PPR    (IN_W / 2)   // 64 float2-pairs per input row

__global__ __launch_bounds__(256) void idwt2_haar_kernel(
    const float* __restrict__ pa,   // cA  (x)
    const float* __restrict__ ph,   // cH  (LH)
    const float* __restrict__ pv,   // cV  (HL)
    const float* __restrict__ pd,   // cD  (HH)
    float* __restrict__ out,
    int n_pairs)                    // total float2 pairs = N_in / 2
{
    int t = blockIdx.x * blockDim.x + threadIdx.x;
    if (t >= n_pairs) return;

    int row = t >> 6;          // global input row (PPR = 64 pairs/row)
    int q   = t & 63;          // pair index within row
    int in_off = row * IN_W + q * 2;

    float2 a = *(const float2*)(pa + in_off);
    float2 h = *(const float2*)(ph + in_off);
    float2 v = *(const float2*)(pv + in_off);
    float2 d = *(const float2*)(pd + in_off);

    int p  = row >> 7;         // (B*C) plane index
    int hr = row & 127;        // input row within plane
    int o  = p * (OUT_W * OUT_W) + (2 * hr) * OUT_W + q * 4;

    float4 top, bot;
    top.x = (a.x + v.x + h.x + d.x) * 0.5f;   // ee  (col 2j)
    top.y = (a.x - v.x + h.x - d.x) * 0.5f;   // eo  (col 2j+1)
    top.z = (a.y + v.y + h.y + d.y) * 0.5f;
    top.w = (a.y - v.y + h.y - d.y) * 0.5f;
    bot.x = (a.x + v.x - h.x - d.x) * 0.5f;   // oe
    bot.y = (a.x - v.x - h.x + d.x) * 0.5f;   // oo
    bot.z = (a.y + v.y - h.y - d.y) * 0.5f;
    bot.w = (a.y - v.y - h.y + d.y) * 0.5f;

    *(float4*)(out + o)         = top;   // even output row, dense per wave
    *(float4*)(out + o + OUT_W) = bot;   // odd output row, dense per wave
}

extern "C" void kernel_launch(void* const* d_in, const int* in_sizes, int n_in,
                              void* d_out, int out_size, void* d_ws, size_t ws_size,
                              hipStream_t stream) {
    const float* pa = (const float*)d_in[0];  // x   = cA
    const float* ph = (const float*)d_in[1];  // LH  = cH
    const float* pv = (const float*)d_in[2];  // HL  = cV
    const float* pd = (const float*)d_in[3];  // HH  = cD
    float* out = (float*)d_out;

    int n_in_elems = in_sizes[0];             // 16*64*128*128 = 16,777,216
    int n_pairs = n_in_elems / 2;             // 8,388,608

    const int block = 256;
    int grid = (n_pairs + block - 1) / block; // 32768

    idwt2_haar_kernel<<<grid, block, 0, stream>>>(pa, ph, pv, pd, out, n_pairs);
}